// Round 2
// baseline (119.049 us; speedup 1.0000x reference)
//
#include <hip/hip_runtime.h>

// BSplineKAN: out[b,c] = sum_i cp[c,i] * N_{i,3}(clip(x[b,c], -0.99, 0.99))
// Knots: 12 uniform knots on [-1,1], h = 2/11, NOT clamped -> every in-range
// basis function is a translate of the cardinal cubic B-spline. For
// x in [t_j, t_{j+1}), u = (x - t_j)/h:
//   N_{j-3} = (1-u)^3/6, N_{j-2} = (3u^3-6u^2+4)/6,
//   N_{j-1} = (-3u^3+3u^2+3u+1)/6, N_j = u^3/6
// Out-of-range i (i<0 or i>7) are dropped (matches reference's truncated
// Cox-de Boor). Fold cp into per-(channel, interval) cubic coefficients:
//   P_{c,j}(u) = a0 + a1*u + a2*u^2 + a3*u^3
//
// LDS layout: stride padded 11 -> 16 float4/channel, slot XOR-swizzled by
// ((c>>2)&7). Within a 16-lane b128 phase the lane channel stride is 4, so
// masks enumerate 0..7 twice and idx%8 = (j^mask)%8 -> <=2 lanes per bank
// group for ANY data-dependent j (2-way is free, m136). 64*16*16B = 16 KiB.

typedef float floatx4 __attribute__((ext_vector_type(4)));  // native vec for NT builtins

constexpr int CH  = 64;   // channels
constexpr int PCP = 8;    // control points per channel
constexpr int NJ  = 11;   // intervals
constexpr int STR = 16;   // padded+swizzled slots per channel
constexpr int TBL = CH * STR;  // 1024 float4 = 16 KiB

__global__ __launch_bounds__(256) void bspline_kan_kernel(
    const float* __restrict__ x,
    const float* __restrict__ cp,
    float* __restrict__ out,
    int n4)
{
    __shared__ floatx4 tbl[TBL];

    // Build the per-(channel, interval) cubic coefficient table (swizzled).
    for (int t = threadIdx.x; t < CH * NJ; t += 256) {
        int c = t / NJ;
        int j = t - c * NJ;
        float p[4];
#pragma unroll
        for (int r = 0; r < 4; ++r) {
            int i = j - 3 + r;
            p[r] = (i >= 0 && i < PCP) ? cp[c * PCP + i] : 0.0f;
        }
        floatx4 a;
        a.x = (p[0] + 4.0f * p[1] + p[2]) * (1.0f / 6.0f);
        a.y = (p[2] - p[0]) * 0.5f;
        a.z = (p[0] - 2.0f * p[1] + p[2]) * 0.5f;
        a.w = (p[3] - p[0] + 3.0f * (p[1] - p[2])) * (1.0f / 6.0f);
        tbl[c * STR + (j ^ ((c >> 2) & 7))] = a;
    }
    __syncthreads();

    const float inv_h = 5.5f;  // 1 / (2/11)

    int idx    = blockIdx.x * blockDim.x + threadIdx.x;
    int stride = gridDim.x * blockDim.x;
    const floatx4* __restrict__ x4 = (const floatx4*)x;
    floatx4* __restrict__ o4 = (floatx4*)out;

    // 4 consecutive elements = 4 consecutive channels (4 | 64); base_c is
    // loop-invariant since stride*4 % 64 == 0. All 4 share (c>>2).
    int base_c = (idx << 2) & (CH - 1);
    int mask   = (base_c >> 2) & 7;
    int boff   = base_c * STR;

    for (int i = idx; i < n4; i += stride) {
        floatx4 xv = __builtin_nontemporal_load(&x4[i]);
        float r[4];
#pragma unroll
        for (int e = 0; e < 4; ++e) {
            float xx = __builtin_amdgcn_fmed3f(xv[e], -0.99f, 0.99f);
            float fz = fmaf(xx, inv_h, inv_h);   // (xx+1)*5.5 in [0.055, 10.945]
            float fj = floorf(fz);
            int j = (int)fj;                     // guaranteed 0..10
            float u = fz - fj;                   // local coord in [0,1)
            floatx4 a = tbl[boff + e * STR + (j ^ mask)];
            r[e] = fmaf(fmaf(fmaf(a.w, u, a.z), u, a.y), u, a.x);
        }
        floatx4 ov = {r[0], r[1], r[2], r[3]};
        __builtin_nontemporal_store(ov, &o4[i]);
    }
}

extern "C" void kernel_launch(void* const* d_in, const int* in_sizes, int n_in,
                              void* d_out, int out_size, void* d_ws, size_t ws_size,
                              hipStream_t stream) {
    const float* x  = (const float*)d_in[0];   // [262144, 64] fp32
    const float* cp = (const float*)d_in[1];   // [64, 8] fp32
    float* out = (float*)d_out;                // [262144, 64] fp32

    int n4 = in_sizes[0] / 4;                  // 4194304 float4s
    // 2048 blocks = 8 blocks/CU on 256 CUs; 8 grid-stride iters/thread
    // amortizes the LDS table build. LDS 16 KiB * 8 = 128 KiB < 160 KiB.
    bspline_kan_kernel<<<2048, 256, 0, stream>>>(x, cp, out, n4);
}

// Round 3
// 113.410 us; speedup vs baseline: 1.0497x; 1.0497x over previous
//
#include <hip/hip_runtime.h>

// BSplineKAN: out[b,c] = sum_i cp[c,i] * N_{i,3}(clip(x[b,c], -0.99, 0.99))
// Knots: 12 uniform knots on [-1,1], h = 2/11, NOT clamped -> every in-range
// basis function is a translate of the cardinal cubic B-spline. For
// x in [t_j, t_{j+1}), u = (x - t_j)/h:
//   N_{j-3} = (1-u)^3/6, N_{j-2} = (3u^3-6u^2+4)/6,
//   N_{j-1} = (-3u^3+3u^2+3u+1)/6, N_j = u^3/6
// Out-of-range i (i<0 or i>7) are dropped (matches reference's truncated
// Cox-de Boor). Fold cp into per-(channel, interval) cubic coefficients:
//   P_{c,j}(u) = a0 + a1*u + a2*u^2 + a3*u^3
//
// LDS layout: stride padded 11 -> 16 float4/channel, slot XOR-swizzled by
// ((c>>2)&7). Lane channel stride is 4, so within a 16-lane b128 phase the
// masks enumerate 0..7 twice and idx%8 = (j^mask)%8 -> same-j lanes (common:
// ~32% of x clips to j=0 or 10) spread across all 8 bank groups at <=2-way,
// which is free (m136). 64*16*16B = 16 KiB -> 8 blocks/CU fits in 160 KiB.
//
// Each thread processes float4s i and i+256 per iteration: both loads are
// unit-stride coalesced, independent (2x MLP), and map to the SAME 4
// channels since 256*4 % 64 == 0.

typedef float floatx4 __attribute__((ext_vector_type(4)));

constexpr int CH  = 64;   // channels
constexpr int PCP = 8;    // control points per channel
constexpr int NJ  = 11;   // intervals
constexpr int STR = 16;   // padded+swizzled slots per channel
constexpr int TBL = CH * STR;  // 1024 float4 = 16 KiB

__global__ __launch_bounds__(256) void bspline_kan_kernel(
    const float* __restrict__ x,
    const float* __restrict__ cp,
    float* __restrict__ out,
    int n4)
{
    __shared__ floatx4 tbl[TBL];

    // Build the per-(channel, interval) cubic coefficient table (swizzled).
    for (int t = threadIdx.x; t < CH * NJ; t += 256) {
        int c = t / NJ;
        int j = t - c * NJ;
        float p[4];
#pragma unroll
        for (int r = 0; r < 4; ++r) {
            int i = j - 3 + r;
            p[r] = (i >= 0 && i < PCP) ? cp[c * PCP + i] : 0.0f;
        }
        floatx4 a;
        a.x = (p[0] + 4.0f * p[1] + p[2]) * (1.0f / 6.0f);
        a.y = (p[2] - p[0]) * 0.5f;
        a.z = (p[0] - 2.0f * p[1] + p[2]) * 0.5f;
        a.w = (p[3] - p[0] + 3.0f * (p[1] - p[2])) * (1.0f / 6.0f);
        tbl[c * STR + (j ^ ((c >> 2) & 7))] = a;
    }
    __syncthreads();

    const float inv_h = 5.5f;  // 1 / (2/11)

    const floatx4* __restrict__ x4 = (const floatx4*)x;
    floatx4* __restrict__ o4 = (floatx4*)out;

    int t = threadIdx.x;
    // Channels for BOTH float4s handled per iter: base_c..base_c+3
    // (loop stride 512 float4s = 2048 elems, 2048 % 64 == 0).
    int base_c = (t << 2) & (CH - 1);
    int mask   = t & 7;              // == (base_c >> 2) & 7
    int boff   = base_c * STR;

    int stride = gridDim.x << 9;     // 512 float4 per block per iter
    for (int i0 = (blockIdx.x << 9) + t; i0 < n4; i0 += stride) {
        int i1 = i0 + 256;
        floatx4 xa = x4[i0];
        floatx4 xb = x4[i1];
        float ra[4], rb[4];
#pragma unroll
        for (int e = 0; e < 4; ++e) {
            int slotbase = boff + e * STR;

            float xxa = __builtin_amdgcn_fmed3f(xa[e], -0.99f, 0.99f);
            float fza = fmaf(xxa, inv_h, inv_h);   // (x+1)*5.5 in [0.055,10.945]
            float fja = floorf(fza);
            int   ja  = (int)fja;                  // 0..10
            float ua  = fza - fja;
            floatx4 A = tbl[slotbase + (ja ^ mask)];
            ra[e] = fmaf(fmaf(fmaf(A.w, ua, A.z), ua, A.y), ua, A.x);

            float xxb = __builtin_amdgcn_fmed3f(xb[e], -0.99f, 0.99f);
            float fzb = fmaf(xxb, inv_h, inv_h);
            float fjb = floorf(fzb);
            int   jb  = (int)fjb;
            float ub  = fzb - fjb;
            floatx4 B = tbl[slotbase + (jb ^ mask)];
            rb[e] = fmaf(fmaf(fmaf(B.w, ub, B.z), ub, B.y), ub, B.x);
        }
        floatx4 oa = {ra[0], ra[1], ra[2], ra[3]};
        floatx4 ob = {rb[0], rb[1], rb[2], rb[3]};
        o4[i0] = oa;
        o4[i1] = ob;
    }
}

extern "C" void kernel_launch(void* const* d_in, const int* in_sizes, int n_in,
                              void* d_out, int out_size, void* d_ws, size_t ws_size,
                              hipStream_t stream) {
    const float* x  = (const float*)d_in[0];   // [262144, 64] fp32
    const float* cp = (const float*)d_in[1];   // [64, 8] fp32
    float* out = (float*)d_out;                // [262144, 64] fp32

    int n4 = in_sizes[0] / 4;                  // 4194304 float4s (512 | n4)
    // 2048 blocks = 8 blocks/CU on 256 CUs; 4 grid-stride iters/thread
    // (2 float4s per iter) amortizes the LDS table build. 16 KiB * 8 = 128 KiB.
    bspline_kan_kernel<<<2048, 256, 0, stream>>>(x, cp, out, n4);
}

// Round 4
// 113.200 us; speedup vs baseline: 1.0517x; 1.0019x over previous
//
#include <hip/hip_runtime.h>

// BSplineKAN: out[b,c] = sum_i cp[c,i] * N_{i,3}(clip(x[b,c], -0.99, 0.99))
// Knots: 12 uniform knots on [-1,1], h = 2/11, NOT clamped -> every in-range
// basis function is a translate of the cardinal cubic B-spline. For
// x in [t_j, t_{j+1}), u = (x - t_j)/h:
//   N_{j-3} = (1-u)^3/6, N_{j-2} = (3u^3-6u^2+4)/6,
//   N_{j-1} = (-3u^3+3u^2+3u+1)/6, N_j = u^3/6
// Out-of-range i (i<0 or i>7) are dropped (matches reference's truncated
// Cox-de Boor). Fold cp into per-(channel, interval) cubic coefficients:
//   P_{c,j}(u) = a0 + a1*u + a2*u^2 + a3*u^3
//
// LDS layout: stride padded 11 -> 16 float4/channel, slot XOR-swizzled by
// ((c>>2)&7). Lane channel stride is 4, so within a 16-lane b128 phase the
// masks enumerate 0..7 twice and idx%8 = (j^mask)%8 -> same-j lanes (common:
// ~32% of x clips to j=0 or 10) spread across all 8 bank groups at <=2-way,
// which is free (m136). 64*16*16B = 16 KiB.
//
// MLP: each thread processes float4s i0, i0+256, i0+512, i0+768 per
// iteration -> 4 outstanding dwordx4 loads, all unit-stride coalesced, all
// mapping to the SAME 4 channels (1024*4 % 64 == 0). 2 grid-stride sweeps.

typedef float floatx4 __attribute__((ext_vector_type(4)));

constexpr int CH  = 64;   // channels
constexpr int PCP = 8;    // control points per channel
constexpr int NJ  = 11;   // intervals
constexpr int STR = 16;   // padded+swizzled slots per channel
constexpr int TBL = CH * STR;  // 1024 float4 = 16 KiB

__global__ __launch_bounds__(256) void bspline_kan_kernel(
    const float* __restrict__ x,
    const float* __restrict__ cp,
    float* __restrict__ out,
    int n4)
{
    __shared__ floatx4 tbl[TBL];

    // Build the per-(channel, interval) cubic coefficient table (swizzled).
    for (int t = threadIdx.x; t < CH * NJ; t += 256) {
        int c = t / NJ;
        int j = t - c * NJ;
        float p[4];
#pragma unroll
        for (int r = 0; r < 4; ++r) {
            int i = j - 3 + r;
            p[r] = (i >= 0 && i < PCP) ? cp[c * PCP + i] : 0.0f;
        }
        floatx4 a;
        a.x = (p[0] + 4.0f * p[1] + p[2]) * (1.0f / 6.0f);
        a.y = (p[2] - p[0]) * 0.5f;
        a.z = (p[0] - 2.0f * p[1] + p[2]) * 0.5f;
        a.w = (p[3] - p[0] + 3.0f * (p[1] - p[2])) * (1.0f / 6.0f);
        tbl[c * STR + (j ^ ((c >> 2) & 7))] = a;
    }
    __syncthreads();

    const float inv_h = 5.5f;  // 1 / (2/11)

    const floatx4* __restrict__ x4 = (const floatx4*)x;
    floatx4* __restrict__ o4 = (floatx4*)out;

    int t = threadIdx.x;
    // Channels for ALL 4 float4s handled per iter: base_c..base_c+3.
    int base_c = (t << 2) & (CH - 1);
    int mask   = t & 7;              // == (base_c >> 2) & 7
    int boff   = base_c * STR;

    int stride = gridDim.x << 10;    // 1024 float4 per block per iter
    for (int i0 = (blockIdx.x << 10) + t; i0 < n4; i0 += stride) {
        // 4 independent loads issued back-to-back.
        floatx4 xs[4];
#pragma unroll
        for (int q = 0; q < 4; ++q) xs[q] = x4[i0 + (q << 8)];

        floatx4 os[4];
#pragma unroll
        for (int q = 0; q < 4; ++q) {
            float r[4];
#pragma unroll
            for (int e = 0; e < 4; ++e) {
                float xx = __builtin_amdgcn_fmed3f(xs[q][e], -0.99f, 0.99f);
                float fz = fmaf(xx, inv_h, inv_h);   // (x+1)*5.5 in [0.055,10.945]
                int   j  = (int)fz;                  // trunc == floor (fz > 0)
                float u  = __builtin_amdgcn_fractf(fz);
                floatx4 A = tbl[boff + e * STR + (j ^ mask)];
                r[e] = fmaf(fmaf(fmaf(A.w, u, A.z), u, A.y), u, A.x);
            }
            os[q] = (floatx4){r[0], r[1], r[2], r[3]};
        }
#pragma unroll
        for (int q = 0; q < 4; ++q) o4[i0 + (q << 8)] = os[q];
    }
}

extern "C" void kernel_launch(void* const* d_in, const int* in_sizes, int n_in,
                              void* d_out, int out_size, void* d_ws, size_t ws_size,
                              hipStream_t stream) {
    const float* x  = (const float*)d_in[0];   // [262144, 64] fp32
    const float* cp = (const float*)d_in[1];   // [64, 8] fp32
    float* out = (float*)d_out;                // [262144, 64] fp32

    int n4 = in_sizes[0] / 4;                  // 4194304 float4s (1024*2048 | n4)
    // 2048 blocks = 8 blocks/CU on 256 CUs; 2 grid-stride iters/thread
    // (4 float4s per iter) amortizes the LDS table build. 16 KiB LDS/block.
    bspline_kan_kernel<<<2048, 256, 0, stream>>>(x, cp, out, n4);
}

// Round 5
// 112.944 us; speedup vs baseline: 1.0541x; 1.0023x over previous
//
#include <hip/hip_runtime.h>

// BSplineKAN: out[b,c] = sum_i cp[c,i] * N_{i,3}(clip(x[b,c], -0.99, 0.99))
// Knots: 12 uniform knots on [-1,1], h = 2/11, NOT clamped -> every in-range
// basis function is a translate of the cardinal cubic B-spline. For
// x in [t_j, t_{j+1}), u = (x - t_j)/h:
//   N_{j-3} = (1-u)^3/6, N_{j-2} = (3u^3-6u^2+4)/6,
//   N_{j-1} = (-3u^3+3u^2+3u+1)/6, N_j = u^3/6
// Out-of-range i (i<0 or i>7) are dropped (matches reference's truncated
// Cox-de Boor). Fold cp into per-(channel, interval) cubic coefficients:
//   P_{c,j}(u) = a0 + a1*u + a2*u^2 + a3*u^3
//
// LDS layout: stride padded 11 -> 16 float4/channel, slot XOR-swizzled by
// ((c>>2)&7): same-j lanes (~32% of x clips to j=0 or 10) spread across all
// 8 bank groups at <=2-way, which is free (m136). 64*16*16B = 16 KiB.
//
// Exact-cover schedule: 2048 blocks x 256 threads x 8 float4s = 4194304
// float4s — NO grid-stride loop. All 8 dwordx4 loads issued up front
// (copy-like streaming); each quad is stored immediately after its compute
// so live VGPRs stay <= 64 (8 waves/SIMD; occupancy halves past 64, m69).
// All 8 quads map to the SAME 4 channels (quad stride 256*4 % 64 == 0).

typedef float floatx4 __attribute__((ext_vector_type(4)));

constexpr int CH  = 64;   // channels
constexpr int PCP = 8;    // control points per channel
constexpr int NJ  = 11;   // intervals
constexpr int STR = 16;   // padded+swizzled slots per channel
constexpr int TBL = CH * STR;  // 1024 float4 = 16 KiB

__global__ __launch_bounds__(256) void bspline_kan_kernel(
    const float* __restrict__ x,
    const float* __restrict__ cp,
    float* __restrict__ out)
{
    __shared__ floatx4 tbl[TBL];

    // Build the per-(channel, interval) cubic coefficient table (swizzled).
    for (int t = threadIdx.x; t < CH * NJ; t += 256) {
        int c = t / NJ;
        int j = t - c * NJ;
        float p[4];
#pragma unroll
        for (int r = 0; r < 4; ++r) {
            int i = j - 3 + r;
            p[r] = (i >= 0 && i < PCP) ? cp[c * PCP + i] : 0.0f;
        }
        floatx4 a;
        a.x = (p[0] + 4.0f * p[1] + p[2]) * (1.0f / 6.0f);
        a.y = (p[2] - p[0]) * 0.5f;
        a.z = (p[0] - 2.0f * p[1] + p[2]) * 0.5f;
        a.w = (p[3] - p[0] + 3.0f * (p[1] - p[2])) * (1.0f / 6.0f);
        tbl[c * STR + (j ^ ((c >> 2) & 7))] = a;
    }
    __syncthreads();

    const float inv_h = 5.5f;  // 1 / (2/11)

    int t = threadIdx.x;
    int base = (blockIdx.x << 11) + t;          // block covers 2048 float4s
    const floatx4* __restrict__ x4 = (const floatx4*)x;
    floatx4* __restrict__ o4 = (floatx4*)out;

    int base_c = (t << 2) & (CH - 1);           // same for all 8 quads
    int mask   = t & 7;                          // == (base_c >> 2) & 7
    int boff   = base_c * STR;

    // Issue all 8 coalesced dwordx4 loads back-to-back (copy-like).
    floatx4 xs[8];
#pragma unroll
    for (int q = 0; q < 8; ++q) xs[q] = x4[base + (q << 8)];

    // Consume in order; store each quad as soon as it's ready.
#pragma unroll
    for (int q = 0; q < 8; ++q) {
        float r[4];
#pragma unroll
        for (int e = 0; e < 4; ++e) {
            float xx = __builtin_amdgcn_fmed3f(xs[q][e], -0.99f, 0.99f);
            float fz = fmaf(xx, inv_h, inv_h);   // (x+1)*5.5 in [0.055,10.945]
            int   j  = (int)fz;                  // trunc == floor (fz > 0)
            float u  = __builtin_amdgcn_fractf(fz);
            floatx4 A = tbl[boff + e * STR + (j ^ mask)];
            r[e] = fmaf(fmaf(fmaf(A.w, u, A.z), u, A.y), u, A.x);
        }
        o4[base + (q << 8)] = (floatx4){r[0], r[1], r[2], r[3]};
    }
}

extern "C" void kernel_launch(void* const* d_in, const int* in_sizes, int n_in,
                              void* d_out, int out_size, void* d_ws, size_t ws_size,
                              hipStream_t stream) {
    const float* x  = (const float*)d_in[0];   // [262144, 64] fp32
    const float* cp = (const float*)d_in[1];   // [64, 8] fp32
    float* out = (float*)d_out;                // [262144, 64] fp32

    // 4194304 float4s = 2048 blocks x 256 threads x 8 float4s, exact cover.
    // 8 blocks/CU on 256 CUs; LDS 16 KiB x 8 = 128 KiB < 160 KiB.
    bspline_kan_kernel<<<2048, 256, 0, stream>>>(x, cp, out);
}